// Round 17
// baseline (499.611 us; speedup 1.0000x reference)
//
#include <hip/hip_runtime.h>
#include <hip/hip_bf16.h>

// B=2, S=1024, D=2048, NH=8, dqk=128, dv=256, I=8192
#define TOKENS 2048
#define DMODEL 2048
#define SEQ    1024
#define QKVO   6144   // fused q|k|v|o bf16 buffer row stride

typedef __attribute__((ext_vector_type(8))) short bf16x8;
typedef __attribute__((ext_vector_type(4))) short bf16x4;
typedef __attribute__((ext_vector_type(4))) float f32x4;
typedef __attribute__((ext_vector_type(8))) unsigned short u16x8;
typedef __attribute__((ext_vector_type(4))) unsigned short u16x4;

__device__ __forceinline__ float sigmoidf_(float x) { return 1.f / (1.f + expf(-x)); }
__device__ __forceinline__ float softcapf_(float x) { return 15.f * tanhf(x * (1.f / 15.f)); }
__device__ __forceinline__ float logsigf_(float x) {
  return (x >= 0.f) ? -log1pf(expf(-x)) : (x - log1pf(expf(x)));
}
__device__ __forceinline__ unsigned short f2bf(float f) {  // RNE, inputs finite
  unsigned u = __builtin_bit_cast(unsigned, f);
  u += 0x7FFFu + ((u >> 16) & 1u);
  return (unsigned short)(u >> 16);
}
__device__ __forceinline__ float bf2f(unsigned short b) {
  unsigned u = ((unsigned)b) << 16;
  return __builtin_bit_cast(float, u);
}

typedef __attribute__((address_space(3))) void lds_void;
typedef const __attribute__((address_space(1))) void gmem_void;
__device__ __forceinline__ void gload16(const void* g, void* l) {
  __builtin_amdgcn_global_load_lds((gmem_void*)g, (lds_void*)l, 16, 0, 0);
}
__device__ __forceinline__ unsigned lds_off(const void* p) {
  return (unsigned)(size_t)(__attribute__((address_space(3))) const void*)p;
}

#if defined(__has_builtin)
#if __has_builtin(__builtin_amdgcn_mfma_f32_16x16x16bf16_1k)
#define HAVE_MFMA16 1
#endif
#endif

__device__ __forceinline__ f32x4 mfma16_bf16(bf16x4 a, bf16x4 b, f32x4 c) {
#ifdef HAVE_MFMA16
  return __builtin_amdgcn_mfma_f32_16x16x16bf16_1k(a, b, c, 0, 0, 0);
#else
  f32x4 d;
  asm volatile("v_mfma_f32_16x16x16_bf16 %0, %1, %2, %3"
               : "=v"(d) : "v"(a), "v"(b), "v"(c));
  return d;
#endif
}

__device__ __forceinline__ bf16x4 tr_read(unsigned addr) {
  bf16x4 d;
  asm volatile("ds_read_b64_tr_b16 %0, %1" : "=v"(d) : "v"(addr));
  return d;
}

// XCD-chunked (T1) + M-fastest rasterization. Requires gridDim.x*y % 8 == 0.
__device__ __forceinline__ void remap_block(int& bm, int& bn) {
  const int nbx = gridDim.x, nby = gridDim.y;
  const int bid = blockIdx.y * nbx + blockIdx.x;
  const int q = (nbx * nby) >> 3;
  const int lid = (bid & 7) * q + (bid >> 3);
  bm = lid % nby;
  bn = lid / nby;
}

// ---------------------------------------------------------------------------
// 256xBN-tile bf16 MFMA GEMM, counted-vmcnt 3-buffer pipeline (R8-proven).
// NBF = 16-col fragments per wave: 4 -> BN=256 (4 loads/stage, vmcnt(4));
// 2 -> BN=128 (3 loads/stage, vmcnt(3)). 512 thr = 8 waves (2Mx4N),
// acc[8][NBF]/wave. Per iter: vmcnt(LP) -> s_barrier -> stage(t+2) ->
// ds_read+MFMA. Never drains vmcnt to 0 in steady state.
// EPI 0: fp32 out at Cout + z*M*N (split-K via blockIdx.z, kz = z*K).
// EPI 1: bf16.
// ---------------------------------------------------------------------------
template <int EPI, int NBF>
__global__ __launch_bounds__(512) void gemm256(
    const unsigned short* __restrict__ A, const unsigned short* __restrict__ BT,
    void* __restrict__ Cout, int M, int N, int K, int ldk) {
  constexpr int BN = 64 * NBF;
  constexpr int BSZ = BN * 32;              // B tile elements
  __shared__ unsigned short lds[3][8192 + BSZ];  // [buf][A | B]
  const int tid = threadIdx.x;
  int bm, bn;
  remap_block(bm, bn);
  const int m0 = bm * 256, n0 = bn * BN;
  const int wid = tid >> 6, lane = tid & 63;
  const int wr = wid >> 2, wc = wid & 3;  // 2 x 4 waves
  const int fr = lane & 15, fq = lane >> 4;
  const size_t kz = (size_t)blockIdx.z * K;

  const f32x4 zero = {0.f, 0.f, 0.f, 0.f};
  f32x4 acc[8][NBF];
#pragma unroll
  for (int m = 0; m < 8; ++m)
#pragma unroll
    for (int n = 0; n < NBF; ++n) acc[m][n] = zero;

  const int sr = tid >> 2;
  const int sc = tid & 3;
  const int sgc = sc ^ ((sr + (sr >> 2)) & 3);   // pre-swizzled global chunk
  const unsigned short* Asrc = A + kz + (size_t)(m0 + sr) * ldk + sgc * 8;
  const unsigned short* Bsrc = BT + kz + (size_t)(n0 + sr) * ldk + sgc * 8;
  const size_t hstep = (size_t)128 * ldk;
  const int ldst = sr * 32 + sc * 8;

  const int rsw = (fq ^ ((fr + (fr >> 2)) & 3)) * 8;
  const int arow0 = wr * 128 + fr;
  const int brow0 = wc * (16 * NBF) + fr;

  auto stage = [&](int t) {
    const size_t ko = (size_t)t * 32;
    const int bs = t % 3;
    gload16(Asrc + ko, &lds[bs][ldst]);
    gload16(Asrc + ko + hstep, &lds[bs][4096 + ldst]);
    gload16(Bsrc + ko, &lds[bs][8192 + ldst]);
    if (NBF == 4) gload16(Bsrc + ko + hstep, &lds[bs][8192 + 4096 + ldst]);
  };

  const int NT = K >> 5;
  stage(0);
  stage(1);

  for (int t = 0; t < NT; ++t) {
    if (t + 1 < NT) {
      if (NBF == 4) {
        asm volatile("s_waitcnt vmcnt(4)" ::: "memory");
      } else {
        asm volatile("s_waitcnt vmcnt(3)" ::: "memory");
      }
    } else {
      asm volatile("s_waitcnt vmcnt(0)" ::: "memory");
    }
    __builtin_amdgcn_s_barrier();
    if (t + 2 < NT) stage(t + 2);
    const int b = t % 3;
    const unsigned short* la = &lds[b][0];
    const unsigned short* lb = &lds[b][8192];
    bf16x8 bfm[NBF], af[4];
#pragma unroll
    for (int n = 0; n < NBF; ++n)
      bfm[n] = *(const bf16x8*)&lb[(brow0 + n * 16) * 32 + rsw];
#pragma unroll
    for (int m = 0; m < 4; ++m)
      af[m] = *(const bf16x8*)&la[(arow0 + m * 16) * 32 + rsw];
    __builtin_amdgcn_s_setprio(1);
#pragma unroll
    for (int m = 0; m < 4; ++m)
#pragma unroll
      for (int n = 0; n < NBF; ++n)
        acc[m][n] = __builtin_amdgcn_mfma_f32_16x16x32_bf16(af[m], bfm[n],
                                                            acc[m][n], 0, 0, 0);
    __builtin_amdgcn_s_setprio(0);
#pragma unroll
    for (int m = 0; m < 4; ++m)
      af[m] = *(const bf16x8*)&la[(arow0 + 64 + m * 16) * 32 + rsw];
    __builtin_amdgcn_s_setprio(1);
#pragma unroll
    for (int m = 0; m < 4; ++m)
#pragma unroll
      for (int n = 0; n < NBF; ++n)
        acc[4 + m][n] = __builtin_amdgcn_mfma_f32_16x16x32_bf16(
            af[m], bfm[n], acc[4 + m][n], 0, 0, 0);
    __builtin_amdgcn_s_setprio(0);
  }

  const int orow = m0 + wr * 128 + fq * 4;
  const int ocol = n0 + wc * (16 * NBF) + fr;
#pragma unroll
  for (int m = 0; m < 8; ++m) {
#pragma unroll
    for (int n = 0; n < NBF; ++n) {
      const int cc = ocol + n * 16;
#pragma unroll
      for (int j = 0; j < 4; ++j) {
        const int r = orow + m * 16 + j;
        float v = acc[m][n][j];
        if (EPI == 0) {
          ((float*)Cout + (size_t)blockIdx.z * M * N)[(size_t)r * N + cc] = v;
        } else {
          ((unsigned short*)Cout)[(size_t)r * N + cc] = f2bf(v);
        }
      }
    }
  }
}

// ---------------------------------------------------------------------------
// Dual gate/up GEMM on the same 3-buffer skeleton: BM=256, BN=128 PER OUTPUT,
// shared A tile. acc[8][2] x2, 4 gloads/tile, in-register silu(g)*u -> bf16.
// ---------------------------------------------------------------------------
__global__ __launch_bounds__(512) void gemm_dual(
    const unsigned short* __restrict__ A, const unsigned short* __restrict__ BT1,
    const unsigned short* __restrict__ BT2, unsigned short* __restrict__ Cout,
    int M, int N, int K) {
  __shared__ unsigned short lds[3][16384];  // [buf][A:0..8191|B1:8192|B2:12288]
  const int tid = threadIdx.x;
  int bm, bn;
  remap_block(bm, bn);
  const int m0 = bm * 256, n0 = bn * 128;
  const int wid = tid >> 6, lane = tid & 63;
  const int wr = wid >> 2, wc = wid & 3;
  const int fr = lane & 15, fq = lane >> 4;

  const f32x4 zero = {0.f, 0.f, 0.f, 0.f};
  f32x4 acc1[8][2], acc2[8][2];
#pragma unroll
  for (int m = 0; m < 8; ++m)
#pragma unroll
    for (int n = 0; n < 2; ++n) { acc1[m][n] = zero; acc2[m][n] = zero; }

  const int sr = tid >> 2;
  const int sc = tid & 3;
  const int sgc = sc ^ ((sr + (sr >> 2)) & 3);
  const unsigned short* Asrc = A + (size_t)(m0 + sr) * K + sgc * 8;
  const unsigned short* B1src = BT1 + (size_t)(n0 + sr) * K + sgc * 8;
  const unsigned short* B2src = BT2 + (size_t)(n0 + sr) * K + sgc * 8;
  const size_t hstep = (size_t)128 * K;
  const int ldst = sr * 32 + sc * 8;

  const int rsw = (fq ^ ((fr + (fr >> 2)) & 3)) * 8;
  const int arow0 = wr * 128 + fr;
  const int brow0 = wc * 32 + fr;

  auto stage = [&](int t) {
    const size_t ko = (size_t)t * 32;
    const int bs = t % 3;
    gload16(Asrc + ko, &lds[bs][ldst]);
    gload16(Asrc + ko + hstep, &lds[bs][4096 + ldst]);
    gload16(B1src + ko, &lds[bs][8192 + ldst]);
    gload16(B2src + ko, &lds[bs][12288 + ldst]);
  };

  const int NT = K >> 5;
  stage(0);
  stage(1);

  for (int t = 0; t < NT; ++t) {
    if (t + 1 < NT) {
      asm volatile("s_waitcnt vmcnt(4)" ::: "memory");
    } else {
      asm volatile("s_waitcnt vmcnt(0)" ::: "memory");
    }
    __builtin_amdgcn_s_barrier();
    if (t + 2 < NT) stage(t + 2);
    const int b = t % 3;
    const unsigned short* la = &lds[b][0];
    bf16x8 b1[2], b2[2], af[4];
#pragma unroll
    for (int n = 0; n < 2; ++n) {
      b1[n] = *(const bf16x8*)&la[8192 + (brow0 + n * 16) * 32 + rsw];
      b2[n] = *(const bf16x8*)&la[12288 + (brow0 + n * 16) * 32 + rsw];
    }
#pragma unroll
    for (int m = 0; m < 4; ++m)
      af[m] = *(const bf16x8*)&la[(arow0 + m * 16) * 32 + rsw];
    __builtin_amdgcn_s_setprio(1);
#pragma unroll
    for (int m = 0; m < 4; ++m)
#pragma unroll
      for (int n = 0; n < 2; ++n) {
        acc1[m][n] = __builtin_amdgcn_mfma_f32_16x16x32_bf16(af[m], b1[n],
                                                             acc1[m][n], 0, 0, 0);
        acc2[m][n] = __builtin_amdgcn_mfma_f32_16x16x32_bf16(af[m], b2[n],
                                                             acc2[m][n], 0, 0, 0);
      }
    __builtin_amdgcn_s_setprio(0);
#pragma unroll
    for (int m = 0; m < 4; ++m)
      af[m] = *(const bf16x8*)&la[(arow0 + 64 + m * 16) * 32 + rsw];
    __builtin_amdgcn_s_setprio(1);
#pragma unroll
    for (int m = 0; m < 4; ++m)
#pragma unroll
      for (int n = 0; n < 2; ++n) {
        acc1[4 + m][n] = __builtin_amdgcn_mfma_f32_16x16x32_bf16(
            af[m], b1[n], acc1[4 + m][n], 0, 0, 0);
        acc2[4 + m][n] = __builtin_amdgcn_mfma_f32_16x16x32_bf16(
            af[m], b2[n], acc2[4 + m][n], 0, 0, 0);
      }
    __builtin_amdgcn_s_setprio(0);
  }

  const int orow = m0 + wr * 128 + fq * 4;
  const int ocol = n0 + wc * 32 + fr;
#pragma unroll
  for (int m = 0; m < 8; ++m) {
#pragma unroll
    for (int n = 0; n < 2; ++n) {
      const int cc = ocol + n * 16;
#pragma unroll
      for (int j = 0; j < 4; ++j) {
        const int r = orow + m * 16 + j;
        const float g = acc1[m][n][j];
        const float u = acc2[m][n][j];
        Cout[(size_t)r * N + cc] = f2bf(g * sigmoidf_(g) * u);
      }
    }
  }
}

// ---------------------------------------------------------------------------
// 128x128-tile bf16 GEMM (2-phase dbuf + swizzle) — for attn projection.
// ---------------------------------------------------------------------------
template <int EPI>
__global__ __launch_bounds__(256) void gemm_bf16(
    const unsigned short* __restrict__ A, const unsigned short* __restrict__ BT,
    void* __restrict__ Cout, int M, int N, int K) {
  __shared__ unsigned short As[2][128 * 32];
  __shared__ unsigned short Bs[2][128 * 32];
  const int tid = threadIdx.x;
  int bm, bn;
  remap_block(bm, bn);
  const int m0 = bm * 128;
  const int n0 = bn * 128;
  const int wid = tid >> 6;
  const int lane = tid & 63;
  const int wr = wid >> 1, wc = wid & 1;
  const int fr = lane & 15, fq = lane >> 4;

  const f32x4 zero = {0.f, 0.f, 0.f, 0.f};
  f32x4 acc[4][4];
#pragma unroll
  for (int m = 0; m < 4; ++m)
#pragma unroll
    for (int n = 0; n < 4; ++n) acc[m][n] = zero;

  const int srow = tid >> 2;
  const int sc = tid & 3;
  const int sgc = sc ^ ((srow + (srow >> 2)) & 3);
  const int scol = sgc * 8;
  const unsigned short* Ag0 = A + (size_t)(m0 + srow) * K + scol;
  const unsigned short* Ag1 = A + (size_t)(m0 + 64 + srow) * K + scol;
  const unsigned short* Bg0 = BT + (size_t)(n0 + srow) * K + scol;
  const unsigned short* Bg1 = BT + (size_t)(n0 + 64 + srow) * K + scol;
  const int rsw = (fq ^ ((fr + (fr >> 2)) & 3)) * 8;

  gload16(Ag0, &As[0][tid * 8]);
  gload16(Ag1, &As[0][2048 + tid * 8]);
  gload16(Bg0, &Bs[0][tid * 8]);
  gload16(Bg1, &Bs[0][2048 + tid * 8]);
  __syncthreads();

  const int nt = K >> 5;
  for (int t = 0; t < nt; ++t) {
    const int cur = t & 1;
    if (t + 1 < nt) {
      const int k0 = (t + 1) << 5;
      gload16(Ag0 + k0, &As[cur ^ 1][tid * 8]);
      gload16(Ag1 + k0, &As[cur ^ 1][2048 + tid * 8]);
      gload16(Bg0 + k0, &Bs[cur ^ 1][tid * 8]);
      gload16(Bg1 + k0, &Bs[cur ^ 1][2048 + tid * 8]);
    }
    bf16x8 af[4], bfm[4];
#pragma unroll
    for (int m = 0; m < 4; ++m)
      af[m] = *(const bf16x8*)&As[cur][(wr * 64 + m * 16 + fr) * 32 + rsw];
#pragma unroll
    for (int n = 0; n < 4; ++n)
      bfm[n] = *(const bf16x8*)&Bs[cur][(wc * 64 + n * 16 + fr) * 32 + rsw];
    __builtin_amdgcn_s_setprio(1);
#pragma unroll
    for (int m = 0; m < 4; ++m)
#pragma unroll
      for (int n = 0; n < 4; ++n)
        acc[m][n] = __builtin_amdgcn_mfma_f32_16x16x32_bf16(af[m], bfm[n],
                                                            acc[m][n], 0, 0, 0);
    __builtin_amdgcn_s_setprio(0);
    __syncthreads();
  }

  const int orow = m0 + wr * 64 + fq * 4;
  const int ocol = n0 + wc * 64 + fr;
#pragma unroll
  for (int m = 0; m < 4; ++m) {
#pragma unroll
    for (int n = 0; n < 4; ++n) {
      const int cc = ocol + n * 16;
#pragma unroll
      for (int j = 0; j < 4; ++j) {
        const int r = orow + m * 16 + j;
        float v = acc[m][n][j];
        if (EPI == 0) ((float*)Cout)[(size_t)r * N + cc] = v;
        else ((unsigned short*)Cout)[(size_t)r * N + cc] = f2bf(v);
      }
    }
  }
}

// ---------------------------------------------------------------------------
// fp32 [K][N] -> bf16 [N][K] transpose-cast body. 128K x 64N tiles.
// ---------------------------------------------------------------------------
__device__ __forceinline__ void castT_body(
    const float* __restrict__ W, unsigned short* __restrict__ WT, int K, int N) {
  __shared__ float tile[128][65];
  const int n0 = blockIdx.x * 64, k0 = blockIdx.y * 128;
  const int rr = threadIdx.x >> 4;
  const int c4 = (threadIdx.x & 15) * 4;
#pragma unroll
  for (int p = 0; p < 8; ++p) {
    const int r = p * 16 + rr;
    float4 v = *(const float4*)&W[(size_t)(k0 + r) * N + n0 + c4];
    tile[r][c4 + 0] = v.x; tile[r][c4 + 1] = v.y;
    tile[r][c4 + 2] = v.z; tile[r][c4 + 3] = v.w;
  }
  __syncthreads();
  const int kc = (threadIdx.x & 15) * 8;
#pragma unroll
  for (int p = 0; p < 4; ++p) {
    const int n = p * 16 + rr;
    u16x8 o;
#pragma unroll
    for (int j = 0; j < 8; ++j) o[j] = f2bf(tile[kc + j][n]);
    *(u16x8*)&WT[(size_t)(n0 + n) * K + k0 + kc] = o;
  }
}

__global__ __launch_bounds__(256) void castT_kernel(
    const float* __restrict__ W, unsigned short* __restrict__ WT, int K, int N) {
  castT_body(W, WT, K, N);
}

// Batched qkvo+Wout weight cast: z selects Wq/Wk/Wv/Wo/Wout. Grid (32,16,5).
// WoutT parked at WT + 6144*2048 (24..32MB tail of the W region).
__global__ __launch_bounds__(256) void castT5_kernel(
    const float* __restrict__ Wq, const float* __restrict__ Wk,
    const float* __restrict__ Wv, const float* __restrict__ Wo,
    const float* __restrict__ Wout, unsigned short* __restrict__ WT) {
  const int z = blockIdx.z;
  const float* src;
  unsigned short* dst;
  int N;
  if (z == 0)      { src = Wq;   dst = WT;                        N = 1024; }
  else if (z == 1) { src = Wk;   dst = WT + (size_t)1024 * 2048;  N = 1024; }
  else if (z == 2) { src = Wv;   dst = WT + (size_t)2048 * 2048;  N = 2048; }
  else if (z == 3) { src = Wo;   dst = WT + (size_t)4096 * 2048;  N = 2048; }
  else             { src = Wout; dst = WT + (size_t)6144 * 2048;  N = 2048; }
  if (blockIdx.x * 64 >= N) return;
  castT_body(src, dst, 2048, N);
}

// Batched gate/up cast: z=0 -> Wgate into WT1, z=1 -> Wup into WT2.
__global__ __launch_bounds__(256) void castT2_kernel(
    const float* __restrict__ Wgate, const float* __restrict__ Wup,
    unsigned short* __restrict__ WT1, unsigned short* __restrict__ WT2) {
  if (blockIdx.z == 0) castT_body(Wgate, WT1, 2048, 8192);
  else castT_body(Wup, WT2, 2048, 8192);
}

// ---------------------------------------------------------------------------
// [Wi|Wf] (each [2048][8] fp32) -> WT[16][2048] fp32 (rows: isF*8+head)
// ---------------------------------------------------------------------------
__global__ __launch_bounds__(256) void gatesT_kernel(
    const float* __restrict__ Wi, const float* __restrict__ Wf,
    float* __restrict__ WT) {
  const int idx = blockIdx.x * 256 + threadIdx.x;
  const int row = idx >> 11;
  const int d = idx & 2047;
  const float* W = (row < 8) ? Wi : Wf;
  WT[idx] = W[d * 8 + (row & 7)];
}

// ---------------------------------------------------------------------------
// Gate pre-activations (fp32) + fused x -> bf16 cast (xb emission)
// ---------------------------------------------------------------------------
__global__ __launch_bounds__(256) void gates_kernel(
    const float* __restrict__ x, const float* __restrict__ WT,
    const float* __restrict__ bi, const float* __restrict__ bf,
    float* __restrict__ icap, float* __restrict__ fls,
    unsigned short* __restrict__ xb) {
  const int t = blockIdx.x;
  const int tid = threadIdx.x;
  __shared__ float xs[2048];
  *(float4*)&xs[tid * 4] = *(const float4*)&x[(size_t)t * 2048 + tid * 4];
  *(float4*)&xs[1024 + tid * 4] =
      *(const float4*)&x[(size_t)t * 2048 + 1024 + tid * 4];
  __syncthreads();
  {
    u16x8 o;
#pragma unroll
    for (int j = 0; j < 8; ++j) o[j] = f2bf(xs[tid * 8 + j]);
    *(u16x8*)&xb[(size_t)t * 2048 + tid * 8] = o;
  }
  const int wave = tid >> 6, lane = tid & 63;
  const int b = t >> 10, s = t & 1023;
  for (int gg = wave; gg < 16; gg += 4) {
    const int head = gg & 7;
    const int isF = gg >> 3;
    const float* Wrow = WT + (size_t)gg * 2048;
    float acc = 0.f;
#pragma unroll
    for (int it = 0; it < 8; ++it) {
      const float4 w4 = *(const float4*)&Wrow[it * 256 + lane * 4];
      const float4 x4 = *(const float4*)&xs[it * 256 + lane * 4];
      acc = fmaf(x4.x, w4.x, acc);
      acc = fmaf(x4.y, w4.y, acc);
      acc = fmaf(x4.z, w4.z, acc);
      acc = fmaf(x4.w, w4.w, acc);
    }
#pragma unroll
    for (int m = 32; m > 0; m >>= 1) acc += __shfl_down(acc, m, 64);
    if (lane == 0) {
      const size_t o = (size_t)(b * 8 + head) * 1024 + s;
      if (isF) fls[o] = logsigf_(softcapf_(acc + bf[head]));
      else icap[o] = softcapf_(acc + bi[head]);
    }
  }
}

// ---------------------------------------------------------------------------
// Per-(b,h) scans: lfc = cumsum(fls); g = icap - lfc; mx = cummax(g)
// ---------------------------------------------------------------------------
__global__ __launch_bounds__(1024) void scan_kernel(
    const float* __restrict__ icap, const float* __restrict__ fls,
    float* __restrict__ lfc, float* __restrict__ garr, float* __restrict__ mx) {
  const int bh = blockIdx.x;
  const int tid = threadIdx.x;
  __shared__ float sm[1024];
  sm[tid] = fls[(size_t)bh * 1024 + tid];
  __syncthreads();
  for (int off = 1; off < 1024; off <<= 1) {
    float v = sm[tid];
    if (tid >= off) v += sm[tid - off];
    __syncthreads();
    sm[tid] = v;
    __syncthreads();
  }
  const float l = sm[tid];
  lfc[(size_t)bh * 1024 + tid] = l;
  const float g = icap[(size_t)bh * 1024 + tid] - l;
  garr[(size_t)bh * 1024 + tid] = g;
  __syncthreads();
  sm[tid] = g;
  __syncthreads();
  for (int off = 1; off < 1024; off <<= 1) {
    float v = sm[tid];
    if (tid >= off) v = fmaxf(v, sm[tid - off]);
    __syncthreads();
    sm[tid] = v;
    __syncthreads();
  }
  mx[(size_t)bh * 1024 + tid] = sm[tid];
}

// ---------------------------------------------------------------------------
// mLSTM core — bf16 MFMA flash-style (swapped QK^T, tr_read V), fused
// multi-head RMS + output gate epilogue. 32-row t-blocks, 128 thr (2 waves),
// 512 blocks with work-balanced tb remap. houtb must NOT alias garr/lfc/mx.
// ---------------------------------------------------------------------------
__global__ __launch_bounds__(128) void mlstm_mfma_kernel(
    const unsigned short* __restrict__ qkvob,
    const float* __restrict__ garr, const float* __restrict__ lfc,
    const float* __restrict__ mx, const float* __restrict__ mhw,
    unsigned short* __restrict__ houtb) {
  __shared__ unsigned short k_lds[32 * 128];
  __shared__ unsigned short v_lds[32 * 256];
  const int tid = threadIdx.x;
  const int lane = tid & 63;
  const int w = tid >> 6;
  const int bh = blockIdx.y;
  const int b = bh >> 3, hh = bh & 7;
  const int tb = (blockIdx.y < 8) ? blockIdx.x : (31 - blockIdx.x);
  const int fr = lane & 15, fq = lane >> 4;
  const int tw = tb * 32 + w * 16 + fr;
  const size_t tokT = (size_t)(b * SEQ + tw);
  const float scale = 0.08838834764831845f;  // 128^-0.5

  bf16x8 qf[4];
#pragma unroll
  for (int kd = 0; kd < 4; ++kd)
    qf[kd] = *(const bf16x8*)&qkvob[tokT * QKVO + hh * 128 + kd * 32 + fq * 8];

  const float Mt = mx[(size_t)bh * SEQ + tw];
  const float mt = lfc[(size_t)bh * SEQ + tw] + Mt;

  f32x4 acc[16];
  const f32x4 zero = {0.f, 0.f, 0.f, 0.f};
#pragma unroll
  for (int D = 0; D < 16; ++D) acc[D] = zero;
  float asum = 0.f;

  const unsigned vbase = lds_off(v_lds);
  const int nsb = tb + 1;

  for (int sb = 0; sb < nsb; ++sb) {
    const int s0 = sb * 32;
    if (sb) __syncthreads();
#pragma unroll
    for (int it = 0; it < 4; ++it) {
      const int ck = it * 128 + tid;
      const int s = ck >> 4, c = ck & 15;
      const int cg = c ^ (s & 7);
      gload16(&qkvob[(size_t)(b * SEQ + s0 + s) * QKVO + 1024 + hh * 128 + cg * 8],
              &k_lds[ck * 8]);
    }
#pragma unroll
    for (int it = 0; it < 8; ++it) {
      const int cv = it * 128 + tid;
      const int W_ = cv >> 9, D = (cv >> 5) & 15, g = (cv >> 3) & 3,
                jj = (cv >> 1) & 3, c2 = cv & 1;
      const int s = W_ * 16 + g * 4 + jj;
      gload16(&qkvob[(size_t)(b * SEQ + s0 + s) * QKVO + 2048 + hh * 256 +
                     D * 16 + c2 * 8],
              &v_lds[cv * 8]);
    }
    __syncthreads();

#pragma unroll
    for (int st = 0; st < 2; ++st) {
      f32x4 cfrag = zero;
      const int srow = st * 16 + fr;
#pragma unroll
      for (int kd = 0; kd < 4; ++kd) {
        const int cc = (kd * 4 + fq) ^ (srow & 7);
        const bf16x8 kf = *(const bf16x8*)&k_lds[srow * 128 + cc * 8];
        cfrag = __builtin_amdgcn_mfma_f32_16x16x32_bf16(kf, qf[kd], cfrag, 0, 0, 0);
      }
      const int sbase = s0 + st * 16 + fq * 4;
      const float4 g4 = *(const float4*)&garr[(size_t)bh * SEQ + sbase];
      float wv[4];
      wv[0] = (sbase + 0 <= tw) ? cfrag[0] * scale * __expf(g4.x - Mt) : 0.f;
      wv[1] = (sbase + 1 <= tw) ? cfrag[1] * scale * __expf(g4.y - Mt) : 0.f;
      wv[2] = (sbase + 2 <= tw) ? cfrag[2] * scale * __expf(g4.z - Mt) : 0.f;
      wv[3] = (sbase + 3 <= tw) ? cfrag[3] * scale * __expf(g4.w - Mt) : 0.f;
      asum += wv[0] + wv[1] + wv[2] + wv[3];
      bf16x4 pf;
      pf[0] = (short)f2bf(wv[0]); pf[1] = (short)f2bf(wv[1]);
      pf[2] = (short)f2bf(wv[2]); pf[3] = (short)f2bf(wv[3]);

#pragma unroll
      for (int Dg = 0; Dg < 2; ++Dg) {
        bf16x4 vf[8];
#pragma unroll
        for (int D = 0; D < 8; ++D)
          vf[D] = tr_read(vbase + (st * 4096 + (Dg * 8 + D) * 256) * 2 + lane * 8);
        asm volatile("s_waitcnt lgkmcnt(0)" ::: "memory");
        __builtin_amdgcn_sched_barrier(0);
#pragma unroll
        for (int D = 0; D < 8; ++D)
          acc[Dg * 8 + D] = mfma16_bf16(vf[D], pf, acc[Dg * 8 + D]);
      }
    }
  }

  asum += __shfl_xor(asum, 16, 64);
  asum += __shfl_xor(asum, 32, 64);
  const float nrm = fmaxf(fabsf(asum), __expf(-mt));
  const float inv = 1.f / (nrm + 1e-6f);
  asm volatile("s_nop 7\n\ts_nop 7" ::);  // MFMA->VALU guard (asm-mfma path)

  // ---- fused multi-head RMS + output gate (token tw, head hh) ----
  float hv[16][4];
  float ss = 0.f;
#pragma unroll
  for (int D = 0; D < 16; ++D)
#pragma unroll
    for (int j = 0; j < 4; ++j) {
      const float v = acc[D][j] * inv;
      hv[D][j] = v;
      ss += v * v;
    }
  ss += __shfl_xor(ss, 16, 64);
  ss += __shfl_xor(ss, 32, 64);
  const float rinv = rsqrtf(ss * (1.f / 256.f) + 1e-6f);
  unsigned short* hrow = &houtb[tokT * 2048 + hh * 256];
  const unsigned short* orow = &qkvob[tokT * QKVO + 4096 + hh * 256];
  const float* mrow = &mhw[hh * 256];
#pragma unroll
  for (int D = 0; D < 16; ++D) {
    const int d0 = D * 16 + fq * 4;
    const float4 m4 = *(const float4*)&mrow[d0];
    const u16x4 o4 = *(const u16x4*)&orow[d0];
    u16x4 res;
    res[0] = f2bf(hv[D][0] * rinv * m4.x * sigmoidf_(bf2f(o4[0])));
    res[1] = f2bf(hv[D][1] * rinv * m4.y * sigmoidf_(bf2f(o4[1])));
    res[2] = f2bf(hv[D][2] * rinv * m4.z * sigmoidf_(bf2f(o4[2])));
    res[3] = f2bf(hv[D][3] * rinv * m4.w * sigmoidf_(bf2f(o4[3])));
    *(u16x4*)&hrow[d0] = res;
  }
}

// ---------------------------------------------------------------------------
// out = base + w * y * rsqrt(mean(y^2)+eps); y = y0 (+ y1 if NY==2).
// EMIT_BF16: also write bf16 copy of out.
// ---------------------------------------------------------------------------
template <int EMIT_BF16, int NY>
__global__ __launch_bounds__(256) void addrms_kernel(
    const float* __restrict__ base_, const float* __restrict__ y0,
    const float* __restrict__ y1, const float* __restrict__ w,
    float* __restrict__ outp, unsigned short* __restrict__ outb) {
  const int t = blockIdx.x;
  const int tid = threadIdx.x;
  __shared__ float red[4];
  const size_t boff = (size_t)t * 2048 + tid * 8;
  float vals[8];
  *(float4*)&vals[0] = *(const float4*)&y0[boff];
  *(float4*)&vals[4] = *(const float4*)&y0[boff + 4];
  if (NY == 2) {
    float v1[8];
    *(float4*)&v1[0] = *(const float4*)&y1[boff];
    *(float4*)&v1[4] = *(const float4*)&y1[boff + 4];
#pragma unroll
    for (int j = 0; j < 8; ++j) vals[j] += v1[j];
  }
  float ss = 0.f;
#pragma unroll
  for (int j = 0; j < 8; ++j) ss += vals[j] * vals[j];
#pragma unroll
  for (int m = 32; m > 0; m >>= 1) ss += __shfl_xor(ss, m, 64);
  if ((tid & 63) == 0) red[tid >> 6] = ss;
  __syncthreads();
  ss = red[0] + red[1] + red[2] + red[3];
  const float rinv = rsqrtf(ss * (1.f / 2048.f) + 1e-6f);
  float bv[8];
  *(float4*)&bv[0] = *(const float4*)&base_[boff];
  *(float4*)&bv[4] = *(const float4*)&base_[boff + 4];
  float res[8];
  u16x8 rb;
#pragma unroll
  for (int j = 0; j < 8; ++j) {
    res[j] = bv[j] + vals[j] * rinv * w[tid * 8 + j];
    if (EMIT_BF16) rb[j] = f2bf(res[j]);
  }
  *(float4*)&outp[boff] = *(float4*)&res[0];
  *(float4*)&outp[boff + 4] = *(float4*)&res[4];
  if (EMIT_BF16) *(u16x8*)&outb[boff] = rb;
}

// ---------------------------------------------------------------------------
extern "C" void kernel_launch(void* const* d_in, const int* in_sizes, int n_in,
                              void* d_out, int out_size, void* d_ws,
                              size_t ws_size, hipStream_t stream) {
  const float* x = (const float*)d_in[0];
  const float* Wq = (const float*)d_in[1];
  const float* Wk = (const float*)d_in[2];
  const float* Wv = (const float*)d_in[3];
  const float* Wo = (const float*)d_in[4];
  const float* Wi = (const float*)d_in[5];
  const float* bi = (const float*)d_in[6];
  const float* Wf = (const float*)d_in[7];
  const float* bf = (const float*)d_in[8];
  const float* mhw = (const float*)d_in[9];
  const float* Wout = (const float*)d_in[10];
  const float* rms1 = (const float*)d_in[11];
  const float* Wgate = (const float*)d_in[12];
  const float* Wup = (const float*)d_in[13];
  const float* Wdown = (const float*)d_in[14];
  const float* rms2 = (const float*)d_in[15];
  float* out = (float*)d_out;
  char* base = (char*)d_ws;
  const size_t MBy = 1024 * 1024;

  // Workspace (MB offsets), peak 144 MB:
  //   0.. 32 W       (qkvo weights 0..24 + WoutT 24..32; later WgateT 0..32)
  //  32.. 64 actb    (dual output; written AFTER houtb is dead)
  //  48.. 49 gs+gwT  (gates..mlstm — mlstm reads these)
  //  56.. 64 houtb   (mlstm..attn)
  //  64.. 80 f1      (addrms1+)
  //  80..112 WupT    (dual) -> mlp partials 80..112 (down+, split-K=2)
  // 112..120 xb -> f1b
  // 120..144 qkvob bf16 -> attn fp32 120..136
  unsigned short* W = (unsigned short*)(base);
  unsigned short* actb = (unsigned short*)(base + 32 * MBy);
  float* gs = (float*)(base + 48 * MBy);
  unsigned short* houtb = (unsigned short*)(base + 56 * MBy);
  float* f1 = (float*)(base + 64 * MBy);
  unsigned short* WupT = (unsigned short*)(base + 80 * MBy);
  float* mlp = (float*)(base + 80 * MBy);  // 2 partials x 16MB: 80..112
  unsigned short* xb = (unsigned short*)(base + 112 * MBy);
  unsigned short* f1b = (unsigned short*)(base + 112 * MBy);
  unsigned short* qkvob = (unsigned short*)(base + 120 * MBy);
  float* attn = (float*)(base + 120 * MBy);
  float* icap = gs;
  float* fls = gs + 16384;
  float* lfc = gs + 32768;
  float* garr = gs + 49152;
  float* mxp = gs + 65536;
  float* gwT = gs + 81920;

  const dim3 blk(256);

  gatesT_kernel<<<128, blk, 0, stream>>>(Wi, Wf, gwT);
  gates_kernel<<<TOKENS, blk, 0, stream>>>(x, gwT, bi, bf, icap, fls, xb);
  scan_kernel<<<16, 1024, 0, stream>>>(icap, fls, lfc, garr, mxp);

  // All qkvo + Wout weight casts in one dispatch
  castT5_kernel<<<dim3(32, 16, 5), blk, 0, stream>>>(Wq, Wk, Wv, Wo, Wout, W);

  // Fused qkvo: qkvob bf16 [2048][6144] = xb @ [Wq|Wk|Wv|Wo]
  gemm256<1, 4><<<dim3(24, 8), dim3(512), 0, stream>>>(
      xb, W, qkvob, TOKENS, 6144, 2048, 2048);

  // mLSTM core with fused multi-head-RMS + output gate -> houtb bf16
  mlstm_mfma_kernel<<<dim3(32, 16), dim3(128), 0, stream>>>(
      qkvob, garr, lfc, mxp, mhw, houtb);

  // attn = houtb @ Wout (fp32 out, 128^2 kernel; WoutT at 24..32MB of W)
  gemm_bf16<0><<<dim3(16, 16), blk, 0, stream>>>(
      houtb, W + (size_t)6144 * 2048, attn, TOKENS, 2048, 2048);

  // f1 = x + rms(attn); f1b bf16
  addrms_kernel<1, 1><<<TOKENS, blk, 0, stream>>>(x, attn, nullptr, rms1, f1,
                                                  f1b);

  // MLP: dual gate/up GEMM with in-register silu(gate)*up -> actb bf16
  castT2_kernel<<<dim3(128, 16, 2), blk, 0, stream>>>(Wgate, Wup, W, WupT);
  gemm_dual<<<dim3(64, 8), dim3(512), 0, stream>>>(f1b, W, WupT, actb,
                                                   TOKENS, 8192, 2048);

  // down-proj: BN=128 tiles, split-K=2 (grid 256 blocks; partials 80..112MB)
  castT_kernel<<<dim3(32, 64), blk, 0, stream>>>(Wdown, W, 8192, 2048);
  gemm256<0, 2><<<dim3(16, 8, 2), dim3(512), 0, stream>>>(
      actb, W, mlp, TOKENS, 2048, 4096, 8192);

  // out = f1 + rms(mlp0 + mlp1)
  addrms_kernel<0, 2><<<TOKENS, blk, 0, stream>>>(f1, mlp, mlp + 4194304, rms2,
                                                  out, nullptr);
}

// Round 18
// 494.570 us; speedup vs baseline: 1.0102x; 1.0102x over previous
//
#include <hip/hip_runtime.h>
#include <hip/hip_bf16.h>

// B=2, S=1024, D=2048, NH=8, dqk=128, dv=256, I=8192
#define TOKENS 2048
#define DMODEL 2048
#define SEQ    1024
#define QKVO   6144   // fused q|k|v|o bf16 buffer row stride

typedef __attribute__((ext_vector_type(8))) short bf16x8;
typedef __attribute__((ext_vector_type(4))) short bf16x4;
typedef __attribute__((ext_vector_type(4))) float f32x4;
typedef __attribute__((ext_vector_type(8))) unsigned short u16x8;
typedef __attribute__((ext_vector_type(4))) unsigned short u16x4;

__device__ __forceinline__ float sigmoidf_(float x) { return 1.f / (1.f + expf(-x)); }
__device__ __forceinline__ float softcapf_(float x) { return 15.f * tanhf(x * (1.f / 15.f)); }
__device__ __forceinline__ float logsigf_(float x) {
  return (x >= 0.f) ? -log1pf(expf(-x)) : (x - log1pf(expf(x)));
}
__device__ __forceinline__ unsigned short f2bf(float f) {  // RNE, inputs finite
  unsigned u = __builtin_bit_cast(unsigned, f);
  u += 0x7FFFu + ((u >> 16) & 1u);
  return (unsigned short)(u >> 16);
}
__device__ __forceinline__ float bf2f(unsigned short b) {
  unsigned u = ((unsigned)b) << 16;
  return __builtin_bit_cast(float, u);
}

typedef __attribute__((address_space(3))) void lds_void;
typedef const __attribute__((address_space(1))) void gmem_void;
__device__ __forceinline__ void gload16(const void* g, void* l) {
  __builtin_amdgcn_global_load_lds((gmem_void*)g, (lds_void*)l, 16, 0, 0);
}
__device__ __forceinline__ unsigned lds_off(const void* p) {
  return (unsigned)(size_t)(__attribute__((address_space(3))) const void*)p;
}

#if defined(__has_builtin)
#if __has_builtin(__builtin_amdgcn_mfma_f32_16x16x16bf16_1k)
#define HAVE_MFMA16 1
#endif
#endif

__device__ __forceinline__ f32x4 mfma16_bf16(bf16x4 a, bf16x4 b, f32x4 c) {
#ifdef HAVE_MFMA16
  return __builtin_amdgcn_mfma_f32_16x16x16bf16_1k(a, b, c, 0, 0, 0);
#else
  f32x4 d;
  asm volatile("v_mfma_f32_16x16x16_bf16 %0, %1, %2, %3"
               : "=v"(d) : "v"(a), "v"(b), "v"(c));
  return d;
#endif
}

__device__ __forceinline__ bf16x4 tr_read(unsigned addr) {
  bf16x4 d;
  asm volatile("ds_read_b64_tr_b16 %0, %1" : "=v"(d) : "v"(addr));
  return d;
}

// XCD-chunked (T1) + M-fastest rasterization. Requires gridDim.x*y % 8 == 0.
__device__ __forceinline__ void remap_block(int& bm, int& bn) {
  const int nbx = gridDim.x, nby = gridDim.y;
  const int bid = blockIdx.y * nbx + blockIdx.x;
  const int q = (nbx * nby) >> 3;
  const int lid = (bid & 7) * q + (bid >> 3);
  bm = lid % nby;
  bn = lid / nby;
}

// ---------------------------------------------------------------------------
// 256x256-tile bf16 MFMA GEMM, counted-vmcnt 3-buffer pipeline (R8-proven):
// C[M,N] = A[M,K(ldk)] @ BT[N,K(ldk)]^T. BK=32, 512 thr = 8 waves (2x4),
// acc[8][4]/wave. LDS 96KB triple-buffered. Per iter: vmcnt(4) -> s_barrier
// -> stage(t+2) -> ds_read+MFMA. Never drains vmcnt to 0 in steady state.
// EPI 0: fp32 out at Cout + z*M*N (split-K via blockIdx.z, kz = z*K).
// EPI 1: bf16.
// ---------------------------------------------------------------------------
template <int EPI>
__global__ __launch_bounds__(512) void gemm256(
    const unsigned short* __restrict__ A, const unsigned short* __restrict__ BT,
    void* __restrict__ Cout, int M, int N, int K, int ldk) {
  __shared__ unsigned short lds[3][2][8192];  // [buf][A|B][256 rows x 32 cols]
  const int tid = threadIdx.x;
  int bm, bn;
  remap_block(bm, bn);
  const int m0 = bm * 256, n0 = bn * 256;
  const int wid = tid >> 6, lane = tid & 63;
  const int wr = wid >> 2, wc = wid & 3;  // 2 x 4 waves
  const int fr = lane & 15, fq = lane >> 4;
  const size_t kz = (size_t)blockIdx.z * K;

  const f32x4 zero = {0.f, 0.f, 0.f, 0.f};
  f32x4 acc[8][4];
#pragma unroll
  for (int m = 0; m < 8; ++m)
#pragma unroll
    for (int n = 0; n < 4; ++n) acc[m][n] = zero;

  const int sr = tid >> 2;
  const int sc = tid & 3;
  const int sgc = sc ^ ((sr + (sr >> 2)) & 3);   // pre-swizzled global chunk
  const unsigned short* Asrc = A + kz + (size_t)(m0 + sr) * ldk + sgc * 8;
  const unsigned short* Bsrc = BT + kz + (size_t)(n0 + sr) * ldk + sgc * 8;
  const size_t hstep = (size_t)128 * ldk;
  const int ldst = sr * 32 + sc * 8;

  const int rsw = (fq ^ ((fr + (fr >> 2)) & 3)) * 8;
  const int arow0 = wr * 128 + fr;
  const int brow0 = wc * 64 + fr;

  auto stage = [&](int t) {
    const size_t ko = (size_t)t * 32;
    const int bs = t % 3;
    gload16(Asrc + ko, &lds[bs][0][ldst]);
    gload16(Asrc + ko + hstep, &lds[bs][0][4096 + ldst]);
    gload16(Bsrc + ko, &lds[bs][1][ldst]);
    gload16(Bsrc + ko + hstep, &lds[bs][1][4096 + ldst]);
  };

  const int NT = K >> 5;
  stage(0);
  stage(1);  // 8 loads in flight

  for (int t = 0; t < NT; ++t) {
    if (t + 1 < NT) {
      asm volatile("s_waitcnt vmcnt(4)" ::: "memory");
    } else {
      asm volatile("s_waitcnt vmcnt(0)" ::: "memory");
    }
    __builtin_amdgcn_s_barrier();
    if (t + 2 < NT) stage(t + 2);
    const int b = t % 3;
    const unsigned short* la = &lds[b][0][0];
    const unsigned short* lb = &lds[b][1][0];
    bf16x8 bfm[4], af[4];
#pragma unroll
    for (int n = 0; n < 4; ++n)
      bfm[n] = *(const bf16x8*)&lb[(brow0 + n * 16) * 32 + rsw];
#pragma unroll
    for (int m = 0; m < 4; ++m)
      af[m] = *(const bf16x8*)&la[(arow0 + m * 16) * 32 + rsw];
    __builtin_amdgcn_s_setprio(1);
#pragma unroll
    for (int m = 0; m < 4; ++m)
#pragma unroll
      for (int n = 0; n < 4; ++n)
        acc[m][n] = __builtin_amdgcn_mfma_f32_16x16x32_bf16(af[m], bfm[n],
                                                            acc[m][n], 0, 0, 0);
    __builtin_amdgcn_s_setprio(0);
#pragma unroll
    for (int m = 0; m < 4; ++m)
      af[m] = *(const bf16x8*)&la[(arow0 + 64 + m * 16) * 32 + rsw];
    __builtin_amdgcn_s_setprio(1);
#pragma unroll
    for (int m = 0; m < 4; ++m)
#pragma unroll
      for (int n = 0; n < 4; ++n)
        acc[4 + m][n] = __builtin_amdgcn_mfma_f32_16x16x32_bf16(
            af[m], bfm[n], acc[4 + m][n], 0, 0, 0);
    __builtin_amdgcn_s_setprio(0);
  }

  const int orow = m0 + wr * 128 + fq * 4;
  const int ocol = n0 + wc * 64 + fr;
#pragma unroll
  for (int m = 0; m < 8; ++m) {
#pragma unroll
    for (int n = 0; n < 4; ++n) {
      const int cc = ocol + n * 16;
#pragma unroll
      for (int j = 0; j < 4; ++j) {
        const int r = orow + m * 16 + j;
        float v = acc[m][n][j];
        if (EPI == 0) {
          ((float*)Cout + (size_t)blockIdx.z * M * N)[(size_t)r * N + cc] = v;
        } else {
          ((unsigned short*)Cout)[(size_t)r * N + cc] = f2bf(v);
        }
      }
    }
  }
}

// ---------------------------------------------------------------------------
// Dual gate/up GEMM on the same 3-buffer skeleton: BM=256, BN=128 PER OUTPUT,
// shared A tile. acc[8][2] x2, 4 gloads/tile, in-register silu(g)*u -> bf16.
// ---------------------------------------------------------------------------
__global__ __launch_bounds__(512) void gemm_dual(
    const unsigned short* __restrict__ A, const unsigned short* __restrict__ BT1,
    const unsigned short* __restrict__ BT2, unsigned short* __restrict__ Cout,
    int M, int N, int K) {
  __shared__ unsigned short lds[3][16384];  // [buf][A:0..8191|B1:8192|B2:12288]
  const int tid = threadIdx.x;
  int bm, bn;
  remap_block(bm, bn);
  const int m0 = bm * 256, n0 = bn * 128;
  const int wid = tid >> 6, lane = tid & 63;
  const int wr = wid >> 2, wc = wid & 3;
  const int fr = lane & 15, fq = lane >> 4;

  const f32x4 zero = {0.f, 0.f, 0.f, 0.f};
  f32x4 acc1[8][2], acc2[8][2];
#pragma unroll
  for (int m = 0; m < 8; ++m)
#pragma unroll
    for (int n = 0; n < 2; ++n) { acc1[m][n] = zero; acc2[m][n] = zero; }

  const int sr = tid >> 2;
  const int sc = tid & 3;
  const int sgc = sc ^ ((sr + (sr >> 2)) & 3);
  const unsigned short* Asrc = A + (size_t)(m0 + sr) * K + sgc * 8;
  const unsigned short* B1src = BT1 + (size_t)(n0 + sr) * K + sgc * 8;
  const unsigned short* B2src = BT2 + (size_t)(n0 + sr) * K + sgc * 8;
  const size_t hstep = (size_t)128 * K;
  const int ldst = sr * 32 + sc * 8;

  const int rsw = (fq ^ ((fr + (fr >> 2)) & 3)) * 8;
  const int arow0 = wr * 128 + fr;
  const int brow0 = wc * 32 + fr;

  auto stage = [&](int t) {
    const size_t ko = (size_t)t * 32;
    const int bs = t % 3;
    gload16(Asrc + ko, &lds[bs][ldst]);
    gload16(Asrc + ko + hstep, &lds[bs][4096 + ldst]);
    gload16(B1src + ko, &lds[bs][8192 + ldst]);
    gload16(B2src + ko, &lds[bs][12288 + ldst]);
  };

  const int NT = K >> 5;
  stage(0);
  stage(1);

  for (int t = 0; t < NT; ++t) {
    if (t + 1 < NT) {
      asm volatile("s_waitcnt vmcnt(4)" ::: "memory");
    } else {
      asm volatile("s_waitcnt vmcnt(0)" ::: "memory");
    }
    __builtin_amdgcn_s_barrier();
    if (t + 2 < NT) stage(t + 2);
    const int b = t % 3;
    const unsigned short* la = &lds[b][0];
    bf16x8 b1[2], b2[2], af[4];
#pragma unroll
    for (int n = 0; n < 2; ++n) {
      b1[n] = *(const bf16x8*)&la[8192 + (brow0 + n * 16) * 32 + rsw];
      b2[n] = *(const bf16x8*)&la[12288 + (brow0 + n * 16) * 32 + rsw];
    }
#pragma unroll
    for (int m = 0; m < 4; ++m)
      af[m] = *(const bf16x8*)&la[(arow0 + m * 16) * 32 + rsw];
    __builtin_amdgcn_s_setprio(1);
#pragma unroll
    for (int m = 0; m < 4; ++m)
#pragma unroll
      for (int n = 0; n < 2; ++n) {
        acc1[m][n] = __builtin_amdgcn_mfma_f32_16x16x32_bf16(af[m], b1[n],
                                                             acc1[m][n], 0, 0, 0);
        acc2[m][n] = __builtin_amdgcn_mfma_f32_16x16x32_bf16(af[m], b2[n],
                                                             acc2[m][n], 0, 0, 0);
      }
    __builtin_amdgcn_s_setprio(0);
#pragma unroll
    for (int m = 0; m < 4; ++m)
      af[m] = *(const bf16x8*)&la[(arow0 + 64 + m * 16) * 32 + rsw];
    __builtin_amdgcn_s_setprio(1);
#pragma unroll
    for (int m = 0; m < 4; ++m)
#pragma unroll
      for (int n = 0; n < 2; ++n) {
        acc1[4 + m][n] = __builtin_amdgcn_mfma_f32_16x16x32_bf16(
            af[m], b1[n], acc1[4 + m][n], 0, 0, 0);
        acc2[4 + m][n] = __builtin_amdgcn_mfma_f32_16x16x32_bf16(
            af[m], b2[n], acc2[4 + m][n], 0, 0, 0);
      }
    __builtin_amdgcn_s_setprio(0);
  }

  const int orow = m0 + wr * 128 + fq * 4;
  const int ocol = n0 + wc * 32 + fr;
#pragma unroll
  for (int m = 0; m < 8; ++m) {
#pragma unroll
    for (int n = 0; n < 2; ++n) {
      const int cc = ocol + n * 16;
#pragma unroll
      for (int j = 0; j < 4; ++j) {
        const int r = orow + m * 16 + j;
        const float g = acc1[m][n][j];
        const float u = acc2[m][n][j];
        Cout[(size_t)r * N + cc] = f2bf(g * sigmoidf_(g) * u);
      }
    }
  }
}

// ---------------------------------------------------------------------------
// 128x128-tile bf16 GEMM (2-phase dbuf + swizzle) — for attn projection.
// ---------------------------------------------------------------------------
template <int EPI>
__global__ __launch_bounds__(256) void gemm_bf16(
    const unsigned short* __restrict__ A, const unsigned short* __restrict__ BT,
    void* __restrict__ Cout, int M, int N, int K) {
  __shared__ unsigned short As[2][128 * 32];
  __shared__ unsigned short Bs[2][128 * 32];
  const int tid = threadIdx.x;
  int bm, bn;
  remap_block(bm, bn);
  const int m0 = bm * 128;
  const int n0 = bn * 128;
  const int wid = tid >> 6;
  const int lane = tid & 63;
  const int wr = wid >> 1, wc = wid & 1;
  const int fr = lane & 15, fq = lane >> 4;

  const f32x4 zero = {0.f, 0.f, 0.f, 0.f};
  f32x4 acc[4][4];
#pragma unroll
  for (int m = 0; m < 4; ++m)
#pragma unroll
    for (int n = 0; n < 4; ++n) acc[m][n] = zero;

  const int srow = tid >> 2;
  const int sc = tid & 3;
  const int sgc = sc ^ ((srow + (srow >> 2)) & 3);
  const int scol = sgc * 8;
  const unsigned short* Ag0 = A + (size_t)(m0 + srow) * K + scol;
  const unsigned short* Ag1 = A + (size_t)(m0 + 64 + srow) * K + scol;
  const unsigned short* Bg0 = BT + (size_t)(n0 + srow) * K + scol;
  const unsigned short* Bg1 = BT + (size_t)(n0 + 64 + srow) * K + scol;
  const int rsw = (fq ^ ((fr + (fr >> 2)) & 3)) * 8;

  gload16(Ag0, &As[0][tid * 8]);
  gload16(Ag1, &As[0][2048 + tid * 8]);
  gload16(Bg0, &Bs[0][tid * 8]);
  gload16(Bg1, &Bs[0][2048 + tid * 8]);
  __syncthreads();

  const int nt = K >> 5;
  for (int t = 0; t < nt; ++t) {
    const int cur = t & 1;
    if (t + 1 < nt) {
      const int k0 = (t + 1) << 5;
      gload16(Ag0 + k0, &As[cur ^ 1][tid * 8]);
      gload16(Ag1 + k0, &As[cur ^ 1][2048 + tid * 8]);
      gload16(Bg0 + k0, &Bs[cur ^ 1][tid * 8]);
      gload16(Bg1 + k0, &Bs[cur ^ 1][2048 + tid * 8]);
    }
    bf16x8 af[4], bfm[4];
#pragma unroll
    for (int m = 0; m < 4; ++m)
      af[m] = *(const bf16x8*)&As[cur][(wr * 64 + m * 16 + fr) * 32 + rsw];
#pragma unroll
    for (int n = 0; n < 4; ++n)
      bfm[n] = *(const bf16x8*)&Bs[cur][(wc * 64 + n * 16 + fr) * 32 + rsw];
    __builtin_amdgcn_s_setprio(1);
#pragma unroll
    for (int m = 0; m < 4; ++m)
#pragma unroll
      for (int n = 0; n < 4; ++n)
        acc[m][n] = __builtin_amdgcn_mfma_f32_16x16x32_bf16(af[m], bfm[n],
                                                            acc[m][n], 0, 0, 0);
    __builtin_amdgcn_s_setprio(0);
    __syncthreads();
  }

  const int orow = m0 + wr * 64 + fq * 4;
  const int ocol = n0 + wc * 64 + fr;
#pragma unroll
  for (int m = 0; m < 4; ++m) {
#pragma unroll
    for (int n = 0; n < 4; ++n) {
      const int cc = ocol + n * 16;
#pragma unroll
      for (int j = 0; j < 4; ++j) {
        const int r = orow + m * 16 + j;
        float v = acc[m][n][j];
        if (EPI == 0) ((float*)Cout)[(size_t)r * N + cc] = v;
        else ((unsigned short*)Cout)[(size_t)r * N + cc] = f2bf(v);
      }
    }
  }
}

// ---------------------------------------------------------------------------
// fp32 [K][N] -> bf16 [N][K] transpose-cast body. 128K x 64N tiles.
// ---------------------------------------------------------------------------
__device__ __forceinline__ void castT_body(
    const float* __restrict__ W, unsigned short* __restrict__ WT, int K, int N) {
  __shared__ float tile[128][65];
  const int n0 = blockIdx.x * 64, k0 = blockIdx.y * 128;
  const int rr = threadIdx.x >> 4;
  const int c4 = (threadIdx.x & 15) * 4;
#pragma unroll
  for (int p = 0; p < 8; ++p) {
    const int r = p * 16 + rr;
    float4 v = *(const float4*)&W[(size_t)(k0 + r) * N + n0 + c4];
    tile[r][c4 + 0] = v.x; tile[r][c4 + 1] = v.y;
    tile[r][c4 + 2] = v.z; tile[r][c4 + 3] = v.w;
  }
  __syncthreads();
  const int kc = (threadIdx.x & 15) * 8;
#pragma unroll
  for (int p = 0; p < 4; ++p) {
    const int n = p * 16 + rr;
    u16x8 o;
#pragma unroll
    for (int j = 0; j < 8; ++j) o[j] = f2bf(tile[kc + j][n]);
    *(u16x8*)&WT[(size_t)(n0 + n) * K + k0 + kc] = o;
  }
}

__global__ __launch_bounds__(256) void castT_kernel(
    const float* __restrict__ W, unsigned short* __restrict__ WT, int K, int N) {
  castT_body(W, WT, K, N);
}

// Batched qkvo+Wout weight cast: z selects Wq/Wk/Wv/Wo/Wout. Grid (32,16,5).
// WoutT parked at WT + 6144*2048 (24..32MB tail of the W region).
__global__ __launch_bounds__(256) void castT5_kernel(
    const float* __restrict__ Wq, const float* __restrict__ Wk,
    const float* __restrict__ Wv, const float* __restrict__ Wo,
    const float* __restrict__ Wout, unsigned short* __restrict__ WT) {
  const int z = blockIdx.z;
  const float* src;
  unsigned short* dst;
  int N;
  if (z == 0)      { src = Wq;   dst = WT;                        N = 1024; }
  else if (z == 1) { src = Wk;   dst = WT + (size_t)1024 * 2048;  N = 1024; }
  else if (z == 2) { src = Wv;   dst = WT + (size_t)2048 * 2048;  N = 2048; }
  else if (z == 3) { src = Wo;   dst = WT + (size_t)4096 * 2048;  N = 2048; }
  else             { src = Wout; dst = WT + (size_t)6144 * 2048;  N = 2048; }
  if (blockIdx.x * 64 >= N) return;
  castT_body(src, dst, 2048, N);
}

// Batched gate/up cast: z=0 -> Wgate into WT1, z=1 -> Wup into WT2.
__global__ __launch_bounds__(256) void castT2_kernel(
    const float* __restrict__ Wgate, const float* __restrict__ Wup,
    unsigned short* __restrict__ WT1, unsigned short* __restrict__ WT2) {
  if (blockIdx.z == 0) castT_body(Wgate, WT1, 2048, 8192);
  else castT_body(Wup, WT2, 2048, 8192);
}

// ---------------------------------------------------------------------------
// [Wi|Wf] (each [2048][8] fp32) -> WT[16][2048] fp32 (rows: isF*8+head)
// ---------------------------------------------------------------------------
__global__ __launch_bounds__(256) void gatesT_kernel(
    const float* __restrict__ Wi, const float* __restrict__ Wf,
    float* __restrict__ WT) {
  const int idx = blockIdx.x * 256 + threadIdx.x;
  const int row = idx >> 11;
  const int d = idx & 2047;
  const float* W = (row < 8) ? Wi : Wf;
  WT[idx] = W[d * 8 + (row & 7)];
}

// ---------------------------------------------------------------------------
// Gate pre-activations (fp32) + fused x -> bf16 cast (xb emission)
// ---------------------------------------------------------------------------
__global__ __launch_bounds__(256) void gates_kernel(
    const float* __restrict__ x, const float* __restrict__ WT,
    const float* __restrict__ bi, const float* __restrict__ bf,
    float* __restrict__ icap, float* __restrict__ fls,
    unsigned short* __restrict__ xb) {
  const int t = blockIdx.x;
  const int tid = threadIdx.x;
  __shared__ float xs[2048];
  *(float4*)&xs[tid * 4] = *(const float4*)&x[(size_t)t * 2048 + tid * 4];
  *(float4*)&xs[1024 + tid * 4] =
      *(const float4*)&x[(size_t)t * 2048 + 1024 + tid * 4];
  __syncthreads();
  {
    u16x8 o;
#pragma unroll
    for (int j = 0; j < 8; ++j) o[j] = f2bf(xs[tid * 8 + j]);
    *(u16x8*)&xb[(size_t)t * 2048 + tid * 8] = o;
  }
  const int wave = tid >> 6, lane = tid & 63;
  const int b = t >> 10, s = t & 1023;
  for (int gg = wave; gg < 16; gg += 4) {
    const int head = gg & 7;
    const int isF = gg >> 3;
    const float* Wrow = WT + (size_t)gg * 2048;
    float acc = 0.f;
#pragma unroll
    for (int it = 0; it < 8; ++it) {
      const float4 w4 = *(const float4*)&Wrow[it * 256 + lane * 4];
      const float4 x4 = *(const float4*)&xs[it * 256 + lane * 4];
      acc = fmaf(x4.x, w4.x, acc);
      acc = fmaf(x4.y, w4.y, acc);
      acc = fmaf(x4.z, w4.z, acc);
      acc = fmaf(x4.w, w4.w, acc);
    }
#pragma unroll
    for (int m = 32; m > 0; m >>= 1) acc += __shfl_down(acc, m, 64);
    if (lane == 0) {
      const size_t o = (size_t)(b * 8 + head) * 1024 + s;
      if (isF) fls[o] = logsigf_(softcapf_(acc + bf[head]));
      else icap[o] = softcapf_(acc + bi[head]);
    }
  }
}

// ---------------------------------------------------------------------------
// Per-(b,h) scans: lfc = cumsum(fls); g = icap - lfc; mx = cummax(g)
// ---------------------------------------------------------------------------
__global__ __launch_bounds__(1024) void scan_kernel(
    const float* __restrict__ icap, const float* __restrict__ fls,
    float* __restrict__ lfc, float* __restrict__ garr, float* __restrict__ mx) {
  const int bh = blockIdx.x;
  const int tid = threadIdx.x;
  __shared__ float sm[1024];
  sm[tid] = fls[(size_t)bh * 1024 + tid];
  __syncthreads();
  for (int off = 1; off < 1024; off <<= 1) {
    float v = sm[tid];
    if (tid >= off) v += sm[tid - off];
    __syncthreads();
    sm[tid] = v;
    __syncthreads();
  }
  const float l = sm[tid];
  lfc[(size_t)bh * 1024 + tid] = l;
  const float g = icap[(size_t)bh * 1024 + tid] - l;
  garr[(size_t)bh * 1024 + tid] = g;
  __syncthreads();
  sm[tid] = g;
  __syncthreads();
  for (int off = 1; off < 1024; off <<= 1) {
    float v = sm[tid];
    if (tid >= off) v = fmaxf(v, sm[tid - off]);
    __syncthreads();
    sm[tid] = v;
    __syncthreads();
  }
  mx[(size_t)bh * 1024 + tid] = sm[tid];
}

// ---------------------------------------------------------------------------
// mLSTM core — bf16 MFMA flash-style (swapped QK^T, tr_read V), fused
// multi-head RMS + output gate epilogue. 32-row t-blocks, 128 thr (2 waves),
// 512 blocks with work-balanced tb remap. houtb must NOT alias garr/lfc/mx.
// ---------------------------------------------------------------------------
__global__ __launch_bounds__(128) void mlstm_mfma_kernel(
    const unsigned short* __restrict__ qkvob,
    const float* __restrict__ garr, const float* __restrict__ lfc,
    const float* __restrict__ mx, const float* __restrict__ mhw,
    unsigned short* __restrict__ houtb) {
  __shared__ unsigned short k_lds[32 * 128];
  __shared__ unsigned short v_lds[32 * 256];
  const int tid = threadIdx.x;
  const int lane = tid & 63;
  const int w = tid >> 6;
  const int bh = blockIdx.y;
  const int b = bh >> 3, hh = bh & 7;
  const int tb = (blockIdx.y < 8) ? blockIdx.x : (31 - blockIdx.x);
  const int fr = lane & 15, fq = lane >> 4;
  const int tw = tb * 32 + w * 16 + fr;
  const size_t tokT = (size_t)(b * SEQ + tw);
  const float scale = 0.08838834764831845f;  // 128^-0.5

  bf16x8 qf[4];
#pragma unroll
  for (int kd = 0; kd < 4; ++kd)
    qf[kd] = *(const bf16x8*)&qkvob[tokT * QKVO + hh * 128 + kd * 32 + fq * 8];

  const float Mt = mx[(size_t)bh * SEQ + tw];
  const float mt = lfc[(size_t)bh * SEQ + tw] + Mt;

  f32x4 acc[16];
  const f32x4 zero = {0.f, 0.f, 0.f, 0.f};
#pragma unroll
  for (int D = 0; D < 16; ++D) acc[D] = zero;
  float asum = 0.f;

  const unsigned vbase = lds_off(v_lds);
  const int nsb = tb + 1;

  for (int sb = 0; sb < nsb; ++sb) {
    const int s0 = sb * 32;
    if (sb) __syncthreads();
#pragma unroll
    for (int it = 0; it < 4; ++it) {
      const int ck = it * 128 + tid;
      const int s = ck >> 4, c = ck & 15;
      const int cg = c ^ (s & 7);
      gload16(&qkvob[(size_t)(b * SEQ + s0 + s) * QKVO + 1024 + hh * 128 + cg * 8],
              &k_lds[ck * 8]);
    }
#pragma unroll
    for (int it = 0; it < 8; ++it) {
      const int cv = it * 128 + tid;
      const int W_ = cv >> 9, D = (cv >> 5) & 15, g = (cv >> 3) & 3,
                jj = (cv >> 1) & 3, c2 = cv & 1;
      const int s = W_ * 16 + g * 4 + jj;
      gload16(&qkvob[(size_t)(b * SEQ + s0 + s) * QKVO + 2048 + hh * 256 +
                     D * 16 + c2 * 8],
              &v_lds[cv * 8]);
    }
    __syncthreads();

#pragma unroll
    for (int st = 0; st < 2; ++st) {
      f32x4 cfrag = zero;
      const int srow = st * 16 + fr;
#pragma unroll
      for (int kd = 0; kd < 4; ++kd) {
        const int cc = (kd * 4 + fq) ^ (srow & 7);
        const bf16x8 kf = *(const bf16x8*)&k_lds[srow * 128 + cc * 8];
        cfrag = __builtin_amdgcn_mfma_f32_16x16x32_bf16(kf, qf[kd], cfrag, 0, 0, 0);
      }
      const int sbase = s0 + st * 16 + fq * 4;
      const float4 g4 = *(const float4*)&garr[(size_t)bh * SEQ + sbase];
      float wv[4];
      wv[0] = (sbase + 0 <= tw) ? cfrag[0] * scale * __expf(g4.x - Mt) : 0.f;
      wv[1] = (sbase + 1 <= tw) ? cfrag[1] * scale * __expf(g4.y - Mt) : 0.f;
      wv[2] = (sbase + 2 <= tw) ? cfrag[2] * scale * __expf(g4.z - Mt) : 0.f;
      wv[3] = (sbase + 3 <= tw) ? cfrag[3] * scale * __expf(g4.w - Mt) : 0.f;
      asum += wv[0] + wv[1] + wv[2] + wv[3];
      bf16x4 pf;
      pf[0] = (short)f2bf(wv[0]); pf[1] = (short)f2bf(wv[1]);
      pf[2] = (short)f2bf(wv[2]); pf[3] = (short)f2bf(wv[3]);

#pragma unroll
      for (int Dg = 0; Dg < 2; ++Dg) {
        bf16x4 vf[8];
#pragma unroll
        for (int D = 0; D < 8; ++D)
          vf[D] = tr_read(vbase + (st * 4096 + (Dg * 8 + D) * 256) * 2 + lane * 8);
        asm volatile("s_waitcnt lgkmcnt(0)" ::: "memory");
        __builtin_amdgcn_sched_barrier(0);
#pragma unroll
        for (int D = 0; D < 8; ++D)
          acc[Dg * 8 + D] = mfma16_bf16(vf[D], pf, acc[Dg * 8 + D]);
      }
    }
  }

  asum += __shfl_xor(asum, 16, 64);
  asum += __shfl_xor(asum, 32, 64);
  const float nrm = fmaxf(fabsf(asum), __expf(-mt));
  const float inv = 1.f / (nrm + 1e-6f);
  asm volatile("s_nop 7\n\ts_nop 7" ::);  // MFMA->VALU guard (asm-mfma path)

  // ---- fused multi-head RMS + output gate (token tw, head hh) ----
  float hv[16][4];
  float ss = 0.f;
#pragma unroll
  for (int D = 0; D < 16; ++D)
#pragma unroll
    for (int j = 0; j < 4; ++j) {
      const float v = acc[D][j] * inv;
      hv[D][j] = v;
      ss += v * v;
    }
  ss += __shfl_xor(ss, 16, 64);
  ss += __shfl_xor(ss, 32, 64);
  const float rinv = rsqrtf(ss * (1.f / 256.f) + 1e-6f);
  unsigned short* hrow = &houtb[tokT * 2048 + hh * 256];
  const unsigned short* orow = &qkvob[tokT * QKVO + 4096 + hh * 256];
  const float* mrow = &mhw[hh * 256];
#pragma unroll
  for (int D = 0; D < 16; ++D) {
    const int d0 = D * 16 + fq * 4;
    const float4 m4 = *(const float4*)&mrow[d0];
    const u16x4 o4 = *(const u16x4*)&orow[d0];
    u16x4 res;
    res[0] = f2bf(hv[D][0] * rinv * m4.x * sigmoidf_(bf2f(o4[0])));
    res[1] = f2bf(hv[D][1] * rinv * m4.y * sigmoidf_(bf2f(o4[1])));
    res[2] = f2bf(hv[D][2] * rinv * m4.z * sigmoidf_(bf2f(o4[2])));
    res[3] = f2bf(hv[D][3] * rinv * m4.w * sigmoidf_(bf2f(o4[3])));
    *(u16x4*)&hrow[d0] = res;
  }
}

// ---------------------------------------------------------------------------
// out = base + w * y * rsqrt(mean(y^2)+eps); y = y0 (+ y1+y2+y3 if NY==4).
// EMIT_BF16: also write bf16 copy of out.
// ---------------------------------------------------------------------------
template <int EMIT_BF16, int NY>
__global__ __launch_bounds__(256) void addrms_kernel(
    const float* __restrict__ base_, const float* __restrict__ y0,
    const float* __restrict__ y1, const float* __restrict__ y2,
    const float* __restrict__ y3, const float* __restrict__ w,
    float* __restrict__ outp, unsigned short* __restrict__ outb) {
  const int t = blockIdx.x;
  const int tid = threadIdx.x;
  __shared__ float red[4];
  const size_t boff = (size_t)t * 2048 + tid * 8;
  float vals[8];
  *(float4*)&vals[0] = *(const float4*)&y0[boff];
  *(float4*)&vals[4] = *(const float4*)&y0[boff + 4];
  if (NY == 4) {
    float v1[8];
    *(float4*)&v1[0] = *(const float4*)&y1[boff];
    *(float4*)&v1[4] = *(const float4*)&y1[boff + 4];
#pragma unroll
    for (int j = 0; j < 8; ++j) vals[j] += v1[j];
    *(float4*)&v1[0] = *(const float4*)&y2[boff];
    *(float4*)&v1[4] = *(const float4*)&y2[boff + 4];
#pragma unroll
    for (int j = 0; j < 8; ++j) vals[j] += v1[j];
    *(float4*)&v1[0] = *(const float4*)&y3[boff];
    *(float4*)&v1[4] = *(const float4*)&y3[boff + 4];
#pragma unroll
    for (int j = 0; j < 8; ++j) vals[j] += v1[j];
  }
  float ss = 0.f;
#pragma unroll
  for (int j = 0; j < 8; ++j) ss += vals[j] * vals[j];
#pragma unroll
  for (int m = 32; m > 0; m >>= 1) ss += __shfl_xor(ss, m, 64);
  if ((tid & 63) == 0) red[tid >> 6] = ss;
  __syncthreads();
  ss = red[0] + red[1] + red[2] + red[3];
  const float rinv = rsqrtf(ss * (1.f / 2048.f) + 1e-6f);
  float bv[8];
  *(float4*)&bv[0] = *(const float4*)&base_[boff];
  *(float4*)&bv[4] = *(const float4*)&base_[boff + 4];
  float res[8];
  u16x8 rb;
#pragma unroll
  for (int j = 0; j < 8; ++j) {
    res[j] = bv[j] + vals[j] * rinv * w[tid * 8 + j];
    if (EMIT_BF16) rb[j] = f2bf(res[j]);
  }
  *(float4*)&outp[boff] = *(float4*)&res[0];
  *(float4*)&outp[boff + 4] = *(float4*)&res[4];
  if (EMIT_BF16) *(u16x8*)&outb[boff] = rb;
}

// ---------------------------------------------------------------------------
extern "C" void kernel_launch(void* const* d_in, const int* in_sizes, int n_in,
                              void* d_out, int out_size, void* d_ws,
                              size_t ws_size, hipStream_t stream) {
  const float* x = (const float*)d_in[0];
  const float* Wq = (const float*)d_in[1];
  const float* Wk = (const float*)d_in[2];
  const float* Wv = (const float*)d_in[3];
  const float* Wo = (const float*)d_in[4];
  const float* Wi = (const float*)d_in[5];
  const float* bi = (const float*)d_in[6];
  const float* Wf = (const float*)d_in[7];
  const float* bf = (const float*)d_in[8];
  const float* mhw = (const float*)d_in[9];
  const float* Wout = (const float*)d_in[10];
  const float* rms1 = (const float*)d_in[11];
  const float* Wgate = (const float*)d_in[12];
  const float* Wup = (const float*)d_in[13];
  const float* Wdown = (const float*)d_in[14];
  const float* rms2 = (const float*)d_in[15];
  float* out = (float*)d_out;
  char* base = (char*)d_ws;
  const size_t MBy = 1024 * 1024;

  // Workspace (MB offsets), peak 144 MB:
  //   0.. 32 W       (qkvo weights 0..24 + WoutT 24..32; later WgateT 0..32)
  //  32.. 64 actb    (dual output; written AFTER houtb is dead)
  //  48.. 49 gs+gwT  (gates..mlstm — mlstm reads these)
  //  56.. 64 houtb   (mlstm..attn)
  //  64.. 80 f1      (addrms1+)
  //  80..112 WupT    (dual) -> mlp partials 80..144 (down+, split-K=4)
  // 112..120 xb -> f1b (dead after dual; overwritten by mlp z=2)
  // 120..144 qkvob bf16 -> attn fp32 120..136 (dead after addrms1; mlp z=2/3)
  unsigned short* W = (unsigned short*)(base);
  unsigned short* actb = (unsigned short*)(base + 32 * MBy);
  float* gs = (float*)(base + 48 * MBy);
  unsigned short* houtb = (unsigned short*)(base + 56 * MBy);
  float* f1 = (float*)(base + 64 * MBy);
  unsigned short* WupT = (unsigned short*)(base + 80 * MBy);
  float* mlp = (float*)(base + 80 * MBy);  // 4 partials x 16MB: 80..144
  unsigned short* xb = (unsigned short*)(base + 112 * MBy);
  unsigned short* f1b = (unsigned short*)(base + 112 * MBy);
  unsigned short* qkvob = (unsigned short*)(base + 120 * MBy);
  float* attn = (float*)(base + 120 * MBy);
  float* icap = gs;
  float* fls = gs + 16384;
  float* lfc = gs + 32768;
  float* garr = gs + 49152;
  float* mxp = gs + 65536;
  float* gwT = gs + 81920;

  const dim3 blk(256);

  gatesT_kernel<<<128, blk, 0, stream>>>(Wi, Wf, gwT);
  gates_kernel<<<TOKENS, blk, 0, stream>>>(x, gwT, bi, bf, icap, fls, xb);
  scan_kernel<<<16, 1024, 0, stream>>>(icap, fls, lfc, garr, mxp);

  // All qkvo + Wout weight casts in one dispatch
  castT5_kernel<<<dim3(32, 16, 5), blk, 0, stream>>>(Wq, Wk, Wv, Wo, Wout, W);

  // Fused qkvo: qkvob bf16 [2048][6144] = xb @ [Wq|Wk|Wv|Wo]
  gemm256<1><<<dim3(24, 8), dim3(512), 0, stream>>>(
      xb, W, qkvob, TOKENS, 6144, 2048, 2048);

  // mLSTM core with fused multi-head-RMS + output gate -> houtb bf16
  mlstm_mfma_kernel<<<dim3(32, 16), dim3(128), 0, stream>>>(
      qkvob, garr, lfc, mxp, mhw, houtb);

  // attn = houtb @ Wout (fp32 out, 128^2 kernel; WoutT at 24..32MB of W)
  gemm_bf16<0><<<dim3(16, 16), blk, 0, stream>>>(
      houtb, W + (size_t)6144 * 2048, attn, TOKENS, 2048, 2048);

  // f1 = x + rms(attn); f1b bf16
  addrms_kernel<1, 1><<<TOKENS, blk, 0, stream>>>(
      x, attn, nullptr, nullptr, nullptr, rms1, f1, f1b);

  // MLP: dual gate/up GEMM with in-register silu(gate)*up -> actb bf16
  castT2_kernel<<<dim3(128, 16, 2), blk, 0, stream>>>(Wgate, Wup, W, WupT);
  gemm_dual<<<dim3(64, 8), dim3(512), 0, stream>>>(f1b, W, WupT, actb,
                                                   TOKENS, 8192, 2048);

  // down-proj, split-K=4 (fp32 partials at mlp + z*16MB; overwrites WupT)
  castT_kernel<<<dim3(32, 64), blk, 0, stream>>>(Wdown, W, 8192, 2048);
  gemm256<0><<<dim3(8, 8, 4), dim3(512), 0, stream>>>(
      actb, W, mlp, TOKENS, 2048, 2048, 8192);

  // out = f1 + rms(mlp0+mlp1+mlp2+mlp3)
  addrms_kernel<0, 4><<<TOKENS, blk, 0, stream>>>(
      f1, mlp, mlp + 4194304, mlp + 8388608, mlp + 12582912, rms2, out,
      nullptr);
}